// Round 5
// baseline (539.563 us; speedup 1.0000x reference)
//
#include <hip/hip_runtime.h>
#include <hip/hip_bf16.h>

typedef unsigned short u16;
typedef short s16x8 __attribute__((ext_vector_type(8)));
typedef unsigned int u32x4 __attribute__((ext_vector_type(4)));
typedef float f32x4 __attribute__((ext_vector_type(4)));

#define F_DIM 2048
#define A_DIM 1024
#define H_DIM 1024
#define BATCH 128
#define LLEN  196
#define MROWS (BATCH * LLEN)   // 25088

// prep-kernel block ranges
#define PREP_WENC   2048                 // [0, 2048): W_enc transpose+cast
#define PREP_ATTN2  (PREP_WENC + 64)     // [2048, 2112): attn2 direct (no atomics)
#define PREP_ZSC    (PREP_ATTN2 + 25)    // [2112, 2137): zero scores
#define PREP_ZOUT   (PREP_ZSC + 256)     // [2137, 2393): zero context out
#define PREP_GRID   PREP_ZOUT

__device__ __forceinline__ u16 f2b(float x) {
  union { float f; unsigned int u; } c; c.f = x;
  unsigned int r = (c.u + 0x7fffu + ((c.u >> 16) & 1u)) >> 16;  // RNE
  return (u16)r;
}

// gfx950-native packed fp32->bf16 (RNE); verified identical numerics in R4
__device__ __forceinline__ unsigned int f2b_pk(float a, float b) {
  unsigned int r;
  asm volatile("v_cvt_pk_bf16_f32 %0, %1, %2" : "=v"(r) : "v"(a), "v"(b));
  return r;
}

__device__ __forceinline__ void gload_lds16(const void* g, void* l) {
  __builtin_amdgcn_global_load_lds((const __attribute__((address_space(1))) void*)g,
                                   (__attribute__((address_space(3))) void*)l, 16, 0, 0);
}

// ---------------------------------------------------------------------------
// K0 "prep": one node doing (a) W_enc -> WT bf16 transpose, (b) attn2p direct
// (full K per thread, no atomics/zeroing), (c) zero scores, (d) zero context out.
__global__ void prep_kernel(const float* __restrict__ W, u16* __restrict__ WT,
                            const float* __restrict__ hidden, const float* __restrict__ W_hid,
                            const float* __restrict__ b_hid, const float* __restrict__ b_enc,
                            float* __restrict__ attn2p, float* __restrict__ scores,
                            float* __restrict__ out) {
  __shared__ float tile[32][33];
  __shared__ float hl[8][1024];
  int bid = blockIdx.x, t = threadIdx.x;

  if (bid < PREP_WENC) {
    int kb = (bid & 63) * 32, ab = (bid >> 6) * 32;
    int r = t >> 3, c = (t & 7) * 4;
    float4 v = *(const float4*)&W[(size_t)(kb + r) * A_DIM + ab + c];
    tile[r][c] = v.x; tile[r][c + 1] = v.y; tile[r][c + 2] = v.z; tile[r][c + 3] = v.w;
    __syncthreads();
    ushort4 o;
    o.x = f2b(tile[c + 0][r]);
    o.y = f2b(tile[c + 1][r]);
    o.z = f2b(tile[c + 2][r]);
    o.w = f2b(tile[c + 3][r]);
    *(ushort4*)&WT[(size_t)(ab + r) * F_DIM + kb + c] = o;
  } else if (bid < PREP_ATTN2) {
    int idx = bid - PREP_WENC;          // 0..63
    int a  = (idx & 3) * 256 + t;
    int b0 = (idx >> 2) * 8;
    #pragma unroll
    for (int j = 0; j < 8; ++j) {
      float4 v = *(const float4*)&hidden[(size_t)(b0 + j) * H_DIM + t * 4];
      *(float4*)&hl[j][t * 4] = v;
    }
    __syncthreads();
    float acc[8] = {0.f, 0.f, 0.f, 0.f, 0.f, 0.f, 0.f, 0.f};
    #pragma unroll 8
    for (int k = 0; k < H_DIM; ++k) {
      float w = W_hid[(size_t)k * A_DIM + a];
      #pragma unroll
      for (int j = 0; j < 8; ++j) acc[j] = fmaf(hl[j][k], w, acc[j]);
    }
    float bias = b_hid[a] + b_enc[a];
    #pragma unroll
    for (int j = 0; j < 8; ++j) attn2p[(size_t)(b0 + j) * A_DIM + a] = acc[j] + bias;
  } else if (bid < PREP_ZSC) {
    int i4 = (bid - PREP_ATTN2) * 256 + t;
    if (i4 < MROWS / 4) ((float4*)scores)[i4] = (float4){0.f, 0.f, 0.f, 0.f};
  } else {
    int i4 = (bid - PREP_ZSC) * 256 + t;   // 256 blocks x 1024 floats = 262144 exact
    ((float4*)out)[i4] = (float4){0.f, 0.f, 0.f, 0.f};
  }
}

// ---------------------------------------------------------------------------
// K1: fused GEMM (enc @ W_enc) + relu(.+attn2)·W_full -> scores.
// bf16 in LDS for both operands (R3 read path). A staged via VGPR
// dwordx4 -> v_cvt_pk_bf16_f32 -> ds_write_b128 (no enc pre-cast pass);
// B staged via global_load_lds width=16. XCD-aware 1D grid: 1600 = 25 x (8n x 8m),
// blocks sharing an A-tile have identical id%8 -> same XCD L2.
__global__ void gemm_score(const float* __restrict__ enc, const u16* __restrict__ WT,
                           const float* __restrict__ attn2p, const float* __restrict__ W_full,
                           float* __restrict__ scores) {
  __shared__ __align__(16) u16 As[128 * 32];
  __shared__ __align__(16) u16 Bs[128 * 32];
  __shared__ float wf_lds[128];
  __shared__ float at2_lds[2][128];

  int i = blockIdx.x;
  int g  = i >> 6;
  int r  = i & 63;
  int y  = r >> 3;         // n-tile 0..7
  int gi = r & 7;          // m-tile within group == i%8 == XCD residue
  int mt = g * 8 + gi;
  if (mt >= MROWS / 128) return;

  int n0 = y * 128;
  int m0 = mt * 128;
  int t = threadIdx.x;

  int b0 = m0 / LLEN;
  int bnd = (b0 + 1) * LLEN;
  int b1 = min(b0 + 1, BATCH - 1);

  if (t < 128) {
    wf_lds[t] = W_full[n0 + t];
    at2_lds[0][t] = attn2p[(size_t)b0 * A_DIM + n0 + t];
    at2_lds[1][t] = attn2p[(size_t)b1 * A_DIM + n0 + t];
  }

  int lane = t & 63, wave = t >> 6;
  int wr = wave >> 1, wc = wave & 1;
  int c16 = lane & 15, quad = lane >> 4;

  f32x4 acc[4][4];
  #pragma unroll
  for (int ii = 0; ii < 4; ++ii)
    #pragma unroll
    for (int j = 0; j < 4; ++j) acc[ii][j] = (f32x4){0.f, 0.f, 0.f, 0.f};

  // A: thread covers rows (t>>2) and (t>>2)+64, fp32 cols (t&3)*8..+7
  const float* ap = enc + (size_t)(m0 + (t >> 2)) * F_DIM + (t & 3) * 8;
  u16* aw = As + (t >> 2) * 32 + (t & 3) * 8;
  // B: global_load_lds, wave-uniform dest + lane*16B
  const u16* bgp = WT + (size_t)(n0 + (t >> 2)) * F_DIM + (t & 3) * 8;
  u16* bl = Bs + wave * 512;

  for (int kt = 0; kt < F_DIM; kt += 32) {
    gload_lds16(bgp + kt, bl);
    gload_lds16(bgp + (size_t)64 * F_DIM + kt, bl + 2048);
    float4 a0 = *(const float4*)(ap + kt);
    float4 a1 = *(const float4*)(ap + kt + 4);
    float4 a2 = *(const float4*)(ap + (size_t)64 * F_DIM + kt);
    float4 a3 = *(const float4*)(ap + (size_t)64 * F_DIM + kt + 4);
    u32x4 w0, w1;
    w0.x = f2b_pk(a0.x, a0.y); w0.y = f2b_pk(a0.z, a0.w);
    w0.z = f2b_pk(a1.x, a1.y); w0.w = f2b_pk(a1.z, a1.w);
    w1.x = f2b_pk(a2.x, a2.y); w1.y = f2b_pk(a2.z, a2.w);
    w1.z = f2b_pk(a3.x, a3.y); w1.w = f2b_pk(a3.z, a3.w);
    *(u32x4*)aw = w0;
    *(u32x4*)(aw + 64 * 32) = w1;
    __syncthreads();
    s16x8 af[4], bf[4];
    #pragma unroll
    for (int ii = 0; ii < 4; ++ii) {
      af[ii] = *(const s16x8*)&As[(wr * 64 + ii * 16 + c16) * 32 + quad * 8];
      bf[ii] = *(const s16x8*)&Bs[(wc * 64 + ii * 16 + c16) * 32 + quad * 8];
    }
    #pragma unroll
    for (int mi = 0; mi < 4; ++mi)
      #pragma unroll
      for (int ni = 0; ni < 4; ++ni)
        acc[mi][ni] = __builtin_amdgcn_mfma_f32_16x16x32_bf16(af[mi], bf[ni], acc[mi][ni], 0, 0, 0);
    __syncthreads();
  }

  float wf[4], a2a[4], a2b[4];
  #pragma unroll
  for (int ni = 0; ni < 4; ++ni) {
    int col = wc * 64 + ni * 16 + c16;
    wf[ni] = wf_lds[col];
    a2a[ni] = at2_lds[0][col];
    a2b[ni] = at2_lds[1][col];
  }
  #pragma unroll
  for (int mi = 0; mi < 4; ++mi) {
    #pragma unroll
    for (int rr = 0; rr < 4; ++rr) {
      int row_g = m0 + wr * 64 + mi * 16 + quad * 4 + rr;
      bool hi = row_g >= bnd;
      float p = 0.f;
      #pragma unroll
      for (int ni = 0; ni < 4; ++ni) {
        float v = acc[mi][ni][rr] + (hi ? a2b[ni] : a2a[ni]);
        v = fmaxf(v, 0.f);
        p = fmaf(v, wf[ni], p);
      }
      p += __shfl_xor(p, 1);
      p += __shfl_xor(p, 2);
      p += __shfl_xor(p, 4);
      p += __shfl_xor(p, 8);
      if (c16 == 0) atomicAdd(&scores[row_g], p);
    }
  }
}

// ---------------------------------------------------------------------------
// K2 "ctx": per-block softmax (redundant, trivial: 196 elems) + alpha write +
// context partial sum with atomicAdd. Grid (2 f-chunks, 128 b, 4 L-chunks of 49).
// b_full dropped: softmax-invariant.
__global__ void ctx_kernel(const float* __restrict__ enc, const float* __restrict__ scores,
                           float* __restrict__ out) {
  __shared__ float red[8];
  __shared__ float al[49];
  int b = blockIdx.y, t = threadIdx.x;
  int z = blockIdx.z;

  float s = (t < LLEN) ? scores[b * LLEN + t] : -3.0e38f;
  float m = s;
  #pragma unroll
  for (int o = 1; o <= 32; o <<= 1) m = fmaxf(m, __shfl_xor(m, o));
  if ((t & 63) == 0) red[t >> 6] = m;
  __syncthreads();
  m = fmaxf(fmaxf(red[0], red[1]), fmaxf(red[2], red[3]));
  float e = (t < LLEN) ? expf(s - m) : 0.f;
  float sum = e;
  #pragma unroll
  for (int o = 1; o <= 32; o <<= 1) sum += __shfl_xor(sum, o);
  __syncthreads();
  if ((t & 63) == 0) red[4 + (t >> 6)] = sum;
  __syncthreads();
  sum = red[4] + red[5] + red[6] + red[7];
  float a = e / sum;

  if (blockIdx.x == 0 && z == 0 && t < LLEN)
    out[(size_t)BATCH * F_DIM + b * LLEN + t] = a;

  int l0 = z * 49;
  if (t >= l0 && t < l0 + 49) al[t - l0] = a;
  __syncthreads();

  int f4 = blockIdx.x * 256 + t;
  const float4* e4 = (const float4*)enc + ((size_t)b * LLEN + l0) * (F_DIM / 4) + f4;
  float4 acc = {0.f, 0.f, 0.f, 0.f};
  #pragma unroll 7
  for (int l = 0; l < 49; ++l) {
    float4 v = e4[(size_t)l * (F_DIM / 4)];
    float aa = al[l];
    acc.x = fmaf(v.x, aa, acc.x);
    acc.y = fmaf(v.y, aa, acc.y);
    acc.z = fmaf(v.z, aa, acc.z);
    acc.w = fmaf(v.w, aa, acc.w);
  }
  float* o = out + (size_t)b * F_DIM + f4 * 4;
  atomicAdd(o + 0, acc.x);
  atomicAdd(o + 1, acc.y);
  atomicAdd(o + 2, acc.z);
  atomicAdd(o + 3, acc.w);
}

// ---------------------------------------------------------------------------
extern "C" void kernel_launch(void* const* d_in, const int* in_sizes, int n_in,
                              void* d_out, int out_size, void* d_ws, size_t ws_size,
                              hipStream_t stream) {
  const float* enc    = (const float*)d_in[0];
  const float* hidden = (const float*)d_in[1];
  const float* W_enc  = (const float*)d_in[2];
  const float* b_enc  = (const float*)d_in[3];
  const float* W_hid  = (const float*)d_in[4];
  const float* b_hid  = (const float*)d_in[5];
  const float* W_full = (const float*)d_in[6];
  float* out = (float*)d_out;

  const size_t wt_bytes = (size_t)A_DIM * F_DIM * sizeof(u16);     // 4 MB
  const size_t a2_bytes = (size_t)BATCH * A_DIM * sizeof(float);   // 512 KB
  char* ws = (char*)d_ws;
  u16*   WT     = (u16*)ws;
  float* attn2p = (float*)(ws + wt_bytes);
  float* scores = (float*)(ws + wt_bytes + a2_bytes);

  prep_kernel<<<dim3(PREP_GRID), 256, 0, stream>>>(W_enc, WT, hidden, W_hid, b_hid, b_enc,
                                                   attn2p, scores, out);
  gemm_score<<<dim3(1600), 256, 0, stream>>>(enc, WT, attn2p, W_full, scores);
  ctx_kernel<<<dim3(2, BATCH, 4), 256, 0, stream>>>(enc, scores, out);
}